// Round 1
// baseline (154.489 us; speedup 1.0000x reference)
//
#include <hip/hip_runtime.h>
#include <hip/hip_bf16.h>

using bf16x8 = __attribute__((ext_vector_type(8))) __bf16;
using f32x4  = __attribute__((ext_vector_type(4))) float;
using i32x4  = __attribute__((ext_vector_type(4))) int;

#define BM 128
#define BN 128
#define BK 64
#define NTHR 256

// out[M,N] = x[M,K] @ W^T + bias,  W[n,k] = qw[n,k] * scales[n, k/GS]
__global__ __launch_bounds__(NTHR)
void gptq_gemm(const float* __restrict__ x, const int* __restrict__ qw,
               const float* __restrict__ scales, const float* __restrict__ bias,
               float* __restrict__ out, int M, int N, int K, int NG, int GS) {
  __shared__ __bf16 lds_a[BM * BK];   // 16 KiB, XOR-swizzled 16B slots
  __shared__ __bf16 lds_b[BN * BK];   // 16 KiB

  const int tid  = threadIdx.x;
  const int lane = tid & 63;
  const int wave = tid >> 6;
  const int wr   = wave >> 1;     // 0..1  wave row
  const int wc   = wave & 1;      // 0..1  wave col
  const int tileM = blockIdx.y * BM;
  const int tileN = blockIdx.x * BN;

  const int l15 = lane & 15;
  const int l4  = lane >> 4;      // 0..3

  f32x4 acc[4][4];
#pragma unroll
  for (int m = 0; m < 4; ++m)
#pragma unroll
    for (int n = 0; n < 4; ++n)
      acc[m][n] = (f32x4)0.0f;

  for (int k0 = 0; k0 < K; k0 += BK) {
    const int g = k0 / GS;   // group idx constant across this K-step (64 | k0)

    // ---- stage A: fp32 -> bf16, 4 units of 8 elems per thread ----
#pragma unroll
    for (int i = 0; i < (BM * BK / 8) / NTHR; ++i) {
      int u   = i * NTHR + tid;
      int row = u >> 3;           // 0..127
      int c8  = u & 7;            // 8-elem unit within row
      const f32x4* src =
          reinterpret_cast<const f32x4*>(x + (size_t)(tileM + row) * K + k0 + c8 * 8);
      f32x4 v0 = src[0], v1 = src[1];
      bf16x8 w;
      w[0] = (__bf16)v0[0]; w[1] = (__bf16)v0[1];
      w[2] = (__bf16)v0[2]; w[3] = (__bf16)v0[3];
      w[4] = (__bf16)v1[0]; w[5] = (__bf16)v1[1];
      w[6] = (__bf16)v1[2]; w[7] = (__bf16)v1[3];
      int slot = c8 ^ (row & 7);
      *reinterpret_cast<bf16x8*>(&lds_a[row * BK + slot * 8]) = w;
    }

    // ---- stage B: int32 * scale -> bf16 ----
#pragma unroll
    for (int i = 0; i < (BN * BK / 8) / NTHR; ++i) {
      int u   = i * NTHR + tid;
      int row = u >> 3;
      int c8  = u & 7;
      int gn  = tileN + row;
      const i32x4* src =
          reinterpret_cast<const i32x4*>(qw + (size_t)gn * K + k0 + c8 * 8);
      i32x4 q0 = src[0], q1 = src[1];
      float s = scales[gn * NG + g];
      bf16x8 w;
      w[0] = (__bf16)((float)q0[0] * s); w[1] = (__bf16)((float)q0[1] * s);
      w[2] = (__bf16)((float)q0[2] * s); w[3] = (__bf16)((float)q0[3] * s);
      w[4] = (__bf16)((float)q1[0] * s); w[5] = (__bf16)((float)q1[1] * s);
      w[6] = (__bf16)((float)q1[2] * s); w[7] = (__bf16)((float)q1[3] * s);
      int slot = c8 ^ (row & 7);
      *reinterpret_cast<bf16x8*>(&lds_b[row * BK + slot * 8]) = w;
    }

    __syncthreads();

    // ---- MFMA over this K-step ----
#pragma unroll
    for (int kk = 0; kk < BK; kk += 32) {
      bf16x8 af[4], bfr[4];
#pragma unroll
      for (int m = 0; m < 4; ++m) {
        int row  = wr * 64 + m * 16 + l15;
        int c8   = (kk >> 3) + l4;
        int slot = c8 ^ (row & 7);
        af[m] = *reinterpret_cast<const bf16x8*>(&lds_a[row * BK + slot * 8]);
      }
#pragma unroll
      for (int n = 0; n < 4; ++n) {
        int row  = wc * 64 + n * 16 + l15;
        int c8   = (kk >> 3) + l4;
        int slot = c8 ^ (row & 7);
        bfr[n] = *reinterpret_cast<const bf16x8*>(&lds_b[row * BK + slot * 8]);
      }
#pragma unroll
      for (int m = 0; m < 4; ++m)
#pragma unroll
        for (int n = 0; n < 4; ++n)
          acc[m][n] =
              __builtin_amdgcn_mfma_f32_16x16x32_bf16(af[m], bfr[n], acc[m][n], 0, 0, 0);
    }

    __syncthreads();
  }

  // ---- epilogue: D row = l4*4 + r, col = l15 (verified m89 layout) ----
#pragma unroll
  for (int n = 0; n < 4; ++n) {
    int col  = tileN + wc * 64 + n * 16 + l15;
    float bv = bias[col];
#pragma unroll
    for (int m = 0; m < 4; ++m) {
      int rbase = tileM + wr * 64 + m * 16 + l4 * 4;
#pragma unroll
      for (int r = 0; r < 4; ++r)
        out[(size_t)(rbase + r) * N + col] = acc[m][n][r] + bv;
    }
  }
}

extern "C" void kernel_launch(void* const* d_in, const int* in_sizes, int n_in,
                              void* d_out, int out_size, void* d_ws, size_t ws_size,
                              hipStream_t stream) {
  const float* x      = (const float*)d_in[0];
  const int*   qw     = (const int*)d_in[1];
  const float* scales = (const float*)d_in[2];
  const float* bias   = (const float*)d_in[3];
  float*       out    = (float*)d_out;

  const int OUT = in_sizes[3];            // 11008
  const int IN  = in_sizes[1] / OUT;      // 4096
  const int M   = in_sizes[0] / IN;       // 512
  const int NG  = in_sizes[2] / OUT;      // 32
  const int GS  = IN / NG;                // 128

  dim3 grid(OUT / BN, M / BM);            // (86, 4)
  gptq_gemm<<<grid, NTHR, 0, stream>>>(x, qw, scales, bias, out, M, OUT, IN, NG, GS);
}

// Round 2
// 145.386 us; speedup vs baseline: 1.0626x; 1.0626x over previous
//
#include <hip/hip_runtime.h>
#include <hip/hip_bf16.h>

using bf16x8 = __attribute__((ext_vector_type(8))) __bf16;
using f32x4  = __attribute__((ext_vector_type(4))) float;
using i32x4  = __attribute__((ext_vector_type(4))) int;

#define BM 128
#define BN 128
#define BK 64
#define NTHR 512   // 8 waves: 2 (M) x 4 (N); wave tile 64x32

// out[M,N] = x[M,K] @ W^T + bias,  W[n,k] = qw[n,k] * scales[n, k/GS]
__global__ __launch_bounds__(NTHR, 2)
void gptq_gemm(const float* __restrict__ x, const int* __restrict__ qw,
               const float* __restrict__ scales, const float* __restrict__ bias,
               float* __restrict__ out, int M, int N, int K, int NG, int GS, int gx) {
  __shared__ __bf16 lds_a[2][BM * BK];   // 2 x 16 KiB
  __shared__ __bf16 lds_b[2][BN * BK];   // 2 x 16 KiB

  const int tid  = threadIdx.x;
  const int lane = tid & 63;
  const int wave = tid >> 6;
  const int wr   = wave >> 2;     // 0..1
  const int wc   = wave & 3;      // 0..3

  // XCD-chunked bijective swizzle (grid 344 = 8*43)
  int bid = blockIdx.x;
  int nwg = gridDim.x;
  int swz = bid;
  if ((nwg & 7) == 0) { int cpx = nwg >> 3; swz = (bid & 7) * cpx + (bid >> 3); }
  const int bx = swz % gx;
  const int by = swz / gx;
  const int tileM = by * BM;
  const int tileN = bx * BN;

  const int l15 = lane & 15;
  const int l4  = lane >> 4;      // 0..3

  f32x4 acc[4][2];
#pragma unroll
  for (int m = 0; m < 4; ++m)
#pragma unroll
    for (int n = 0; n < 2; ++n)
      acc[m][n] = (f32x4)0.0f;

  // per-thread staging units: 2 for A, 2 for B (each unit = 8 contiguous k)
  auto loadA = [&](int k0, f32x4 (&va)[2][2]) {
#pragma unroll
    for (int i = 0; i < 2; ++i) {
      int u = i * NTHR + tid, row = u >> 3, c8 = u & 7;
      const f32x4* src =
          reinterpret_cast<const f32x4*>(x + (size_t)(tileM + row) * K + k0 + c8 * 8);
      va[i][0] = src[0]; va[i][1] = src[1];
    }
  };
  auto loadB = [&](int k0, i32x4 (&vb)[2][2], float (&vs)[2]) {
    const int g = k0 / GS;
#pragma unroll
    for (int i = 0; i < 2; ++i) {
      int u = i * NTHR + tid, row = u >> 3, c8 = u & 7;
      int gn = tileN + row;
      const i32x4* src =
          reinterpret_cast<const i32x4*>(qw + (size_t)gn * K + k0 + c8 * 8);
      vb[i][0] = src[0]; vb[i][1] = src[1];
      vs[i] = scales[gn * NG + g];
    }
  };
  auto stageWrite = [&](int buf, const f32x4 (&va)[2][2], const i32x4 (&vb)[2][2],
                        const float (&vs)[2]) {
#pragma unroll
    for (int i = 0; i < 2; ++i) {
      int u = i * NTHR + tid, row = u >> 3, c8 = u & 7;
      int slot = c8 ^ (row & 7);
      bf16x8 wa;
      wa[0] = (__bf16)va[i][0][0]; wa[1] = (__bf16)va[i][0][1];
      wa[2] = (__bf16)va[i][0][2]; wa[3] = (__bf16)va[i][0][3];
      wa[4] = (__bf16)va[i][1][0]; wa[5] = (__bf16)va[i][1][1];
      wa[6] = (__bf16)va[i][1][2]; wa[7] = (__bf16)va[i][1][3];
      *reinterpret_cast<bf16x8*>(&lds_a[buf][row * BK + slot * 8]) = wa;
      float s = vs[i];
      bf16x8 wb;
      wb[0] = (__bf16)((float)vb[i][0][0] * s); wb[1] = (__bf16)((float)vb[i][0][1] * s);
      wb[2] = (__bf16)((float)vb[i][0][2] * s); wb[3] = (__bf16)((float)vb[i][0][3] * s);
      wb[4] = (__bf16)((float)vb[i][1][0] * s); wb[5] = (__bf16)((float)vb[i][1][1] * s);
      wb[6] = (__bf16)((float)vb[i][1][2] * s); wb[7] = (__bf16)((float)vb[i][1][3] * s);
      *reinterpret_cast<bf16x8*>(&lds_b[buf][row * BK + slot * 8]) = wb;
    }
  };

  // prologue: stage tile 0
  {
    f32x4 va[2][2]; i32x4 vb[2][2]; float vs[2];
    loadA(0, va); loadB(0, vb, vs);
    stageWrite(0, va, vb, vs);
  }
  __syncthreads();

  int cur = 0;
  for (int k0 = 0; k0 < K; k0 += BK) {
    const bool pf = (k0 + BK) < K;
    f32x4 va[2][2]; i32x4 vb[2][2]; float vs[2];
    if (pf) { loadA(k0 + BK, va); loadB(k0 + BK, vb, vs); }  // issue early

    // ---- MFMA on buf[cur] ----
#pragma unroll
    for (int kk = 0; kk < BK; kk += 32) {
      bf16x8 af[4], bfr[2];
#pragma unroll
      for (int m = 0; m < 4; ++m) {
        int row  = wr * 64 + m * 16 + l15;
        int c8   = (kk >> 3) + l4;
        int slot = c8 ^ (row & 7);
        af[m] = *reinterpret_cast<const bf16x8*>(&lds_a[cur][row * BK + slot * 8]);
      }
#pragma unroll
      for (int n = 0; n < 2; ++n) {
        int row  = wc * 32 + n * 16 + l15;
        int c8   = (kk >> 3) + l4;
        int slot = c8 ^ (row & 7);
        bfr[n] = *reinterpret_cast<const bf16x8*>(&lds_b[cur][row * BK + slot * 8]);
      }
#pragma unroll
      for (int m = 0; m < 4; ++m)
#pragma unroll
        for (int n = 0; n < 2; ++n)
          acc[m][n] =
              __builtin_amdgcn_mfma_f32_16x16x32_bf16(af[m], bfr[n], acc[m][n], 0, 0, 0);
    }

    if (pf) stageWrite(cur ^ 1, va, vb, vs);   // convert + write next buf
    __syncthreads();
    cur ^= 1;
  }

  // ---- epilogue: D row = l4*4 + r, col = l15 ----
#pragma unroll
  for (int n = 0; n < 2; ++n) {
    int col  = tileN + wc * 32 + n * 16 + l15;
    float bv = bias[col];
#pragma unroll
    for (int m = 0; m < 4; ++m) {
      int rbase = tileM + wr * 64 + m * 16 + l4 * 4;
#pragma unroll
      for (int r = 0; r < 4; ++r)
        out[(size_t)(rbase + r) * N + col] = acc[m][n][r] + bv;
    }
  }
}

extern "C" void kernel_launch(void* const* d_in, const int* in_sizes, int n_in,
                              void* d_out, int out_size, void* d_ws, size_t ws_size,
                              hipStream_t stream) {
  const float* x      = (const float*)d_in[0];
  const int*   qw     = (const int*)d_in[1];
  const float* scales = (const float*)d_in[2];
  const float* bias   = (const float*)d_in[3];
  float*       out    = (float*)d_out;

  const int OUT = in_sizes[3];            // 11008
  const int IN  = in_sizes[1] / OUT;      // 4096
  const int M   = in_sizes[0] / IN;       // 512
  const int NG  = in_sizes[2] / OUT;      // 32
  const int GS  = IN / NG;                // 128

  const int gx = OUT / BN;                // 86
  const int gy = M / BM;                  // 4
  gptq_gemm<<<gx * gy, NTHR, 0, stream>>>(x, qw, scales, bias, out, M, OUT, IN, NG, GS, gx);
}